// Round 6
// baseline (6625.466 us; speedup 1.0000x reference)
//
#include <hip/hip_runtime.h>

// Problem dims (fixed)
#define Bn 64
#define Tn 512
#define En 1024
#define Hn 1024
#define Vn 50257
#define CHUNK 64
#define NCHUNK (Tn / CHUNK)
#define AGENT __HIP_MEMORY_SCOPE_AGENT

typedef __attribute__((ext_vector_type(8))) short short8;
typedef __attribute__((ext_vector_type(4))) float f32x4;
typedef unsigned long long u64;

__device__ __forceinline__ unsigned short f2bf(float f) {
    union { float f; unsigned u; } x; x.f = f;
    unsigned r = x.u + 0x7FFFu + ((x.u >> 16) & 1u);   // RNE; values are tame
    return (unsigned short)(r >> 16);
}
__device__ __forceinline__ float sigm(float x) { return 1.0f / (1.0f + __expf(-x)); }
__device__ __forceinline__ float tanh_fast(float x) {
    float e = __expf(2.0f * x);
    return (e - 1.0f) / (e + 1.0f);
}

// ---------------- fp32 -> bf16 weight convert ----------------
__global__ __launch_bounds__(256)
void cvt_f32_bf16(const float* __restrict__ src, unsigned short* __restrict__ dst, int n4) {
    int i = blockIdx.x * 256 + threadIdx.x;
    if (i < n4) {
        float4 v = reinterpret_cast<const float4*>(src)[i];
        ushort4 o;
        o.x = f2bf(v.x); o.y = f2bf(v.y); o.z = f2bf(v.z); o.w = f2bf(v.w);
        reinterpret_cast<ushort4*>(dst)[i] = o;
    }
}

// ---------------- embedding gather for one 64-step chunk ----------------
__global__ __launch_bounds__(256)
void gather_x(const int* __restrict__ tokens, const float* __restrict__ emb,
              unsigned short* __restrict__ X, int t0) {
    const int r = blockIdx.x;
    const int trel = r >> 6, b = r & 63;
    const int tok = tokens[b * Tn + t0 + trel];
    const float* src = emb + (size_t)tok * En;
    const int k = threadIdx.x * 4;
    float4 v = *reinterpret_cast<const float4*>(src + k);
    ushort4 o;
    o.x = f2bf(v.x); o.y = f2bf(v.y); o.z = f2bf(v.z); o.w = f2bf(v.w);
    *reinterpret_cast<ushort4*>(X + (size_t)r * En + k) = o;
}

// ---------------- G = X @ W_ih^T  (4096 x 4096, K=1024), fp32 out ----------------
__global__ __launch_bounds__(256)
void gemm_gin(const unsigned short* __restrict__ X, const unsigned short* __restrict__ Wih,
              float* __restrict__ G) {
    __shared__ __align__(16) unsigned short As[128][72];
    __shared__ __align__(16) unsigned short Bs[128][72];

    const int tid = threadIdx.x;
    const int bx = blockIdx.x & 31;
    const int by = blockIdx.x >> 5;
    const int w = tid >> 6, l = tid & 63;
    const int wr = w >> 1, wc = w & 1;

    f32x4 acc[4][4];
#pragma unroll
    for (int i = 0; i < 4; ++i)
#pragma unroll
        for (int j = 0; j < 4; ++j) acc[i][j] = (f32x4){0.f, 0.f, 0.f, 0.f};

    const int koff = (l >> 4) * 8;

    for (int kk = 0; kk < En / 64; ++kk) {
        __syncthreads();
#pragma unroll
        for (int j = 0; j < 4; ++j) {
            const int u = tid * 4 + j;
            const int row = u >> 3, ku = (u & 7) * 8;
            *reinterpret_cast<short8*>(&As[row][ku]) =
                *reinterpret_cast<const short8*>(X + (size_t)(by * 128 + row) * En + kk * 64 + ku);
            *reinterpret_cast<short8*>(&Bs[row][ku]) =
                *reinterpret_cast<const short8*>(Wih + (size_t)(bx * 128 + row) * En + kk * 64 + ku);
        }
        __syncthreads();

#pragma unroll
        for (int kc = 0; kc < 2; ++kc) {
            const int k0 = kc * 32 + koff;
            short8 af[4], bf[4];
#pragma unroll
            for (int i = 0; i < 4; ++i)
                af[i] = *reinterpret_cast<const short8*>(&As[wr * 64 + i * 16 + (l & 15)][k0]);
#pragma unroll
            for (int j = 0; j < 4; ++j)
                bf[j] = *reinterpret_cast<const short8*>(&Bs[wc * 64 + j * 16 + (l & 15)][k0]);
#pragma unroll
            for (int i = 0; i < 4; ++i)
#pragma unroll
                for (int j = 0; j < 4; ++j)
                    acc[i][j] = __builtin_amdgcn_mfma_f32_16x16x32_bf16(af[i], bf[j], acc[i][j], 0, 0, 0);
        }
    }

    const int rr = 4 * (l >> 4);
#pragma unroll
    for (int i = 0; i < 4; ++i) {
        const int row = by * 128 + wr * 64 + i * 16 + rr;
#pragma unroll
        for (int j = 0; j < 4; ++j) {
            const int col = bx * 128 + wc * 64 + j * 16 + (l & 15);
#pragma unroll
            for (int r = 0; r < 4; ++r)
                G[(size_t)(row + r) * 4096 + col] = acc[i][j][r];
        }
    }
}

// ---------------- persistent recurrent kernel: 2-stream pipelined ----------
// 128 blocks x 256 threads, <=1 block/CU (co-resident by capacity).
// Batch rows split: stream A = rows 0..31, stream B = rows 32..63 (independent
// recurrences). Streams alternate; each stream's h-prefetch / flag propagation
// overlaps the other stream's compute.
// Block b owns 32 gate-cols (tile0=[i|f] x 8 hcols, tile1=[g|o] x 8 hcols).
// Wave w: kh=w&1 (K-half), rh=w>>1 (16-row half of the 32 stream rows).
// W_hh in 128 VGPRs/lane; h via agent-scope relaxed atomics (IC-coherent);
// per-block flag lines per stream, all-poll-all, bounded spin.
__global__ __launch_bounds__(256, 1)
void lstm_chunk(const float* __restrict__ G, const unsigned short* __restrict__ Whh,
                unsigned short* __restrict__ h0, unsigned short* __restrict__ h1,
                float* __restrict__ c_state, unsigned* __restrict__ flagsA,
                unsigned* __restrict__ flagsB, int t0,
                float* __restrict__ out_h, float* __restrict__ out_c)
{
    __shared__ __align__(16) float red[2][2][64][4];   // [rh][ct][lane][r], reused A/B

    const int tid = threadIdx.x;
    const int b = blockIdx.x;
    const int w = tid >> 6, l = tid & 63;
    const int kh = w & 1, rh = w >> 1;
    const int koff = (l >> 4) * 8;
    const int lc = l & 15;
    const int hcol = b * 8 + (l & 7);
    const int rowL = rh * 16 + ((l >> 4) << 2);      // stream-local row base (cell)
    const int sg = lc >> 3;
    const int gc0 = sg * Hn + hcol;                  // i / f
    const int gc1 = (2 + sg) * Hn + hcol;            // g / o

    // ---- W_hh fragments -> registers (once per launch) ----
    short8 breg[2][16];
#pragma unroll
    for (int ct = 0; ct < 2; ++ct) {
        const int gate = ct * 2 + (lc >> 3);
        const unsigned short* wrow = Whh + ((size_t)gate * Hn + (b * 8 + (lc & 7))) * Hn;
#pragma unroll
        for (int j = 0; j < 16; ++j)
            breg[ct][j] = *reinterpret_cast<const short8*>(wrow + (kh * 16 + j) * 32 + koff);
    }

    // ---- c-state in registers (kh==0 waves own the cell update) ----
    float cA[4], cB[4];
    if (kh == 0) {
#pragma unroll
        for (int r = 0; r < 4; ++r) {
            cA[r] = c_state[(rowL + r) * Hn + hcol];
            cB[r] = c_state[(32 + rowL + r) * Hn + hcol];
        }
    }

    const int arow = rh * 16 + (l & 15);             // stream-local A-fragment row

    // ---- prologue: preload stream A state(t0) (launch boundary = visible) ----
    u64 aA[16][2];
    {
        const unsigned short* hin0 = (t0 & 1) ? h1 : h0;
        const unsigned short* ap = hin0 + (size_t)arow * Hn + kh * 512 + koff;
#pragma unroll
        for (int j = 0; j < 16; ++j) {
            aA[j][0] = __hip_atomic_load((const u64*)(ap + j * 32),     __ATOMIC_RELAXED, AGENT);
            aA[j][1] = __hip_atomic_load((const u64*)(ap + j * 32 + 4), __ATOMIC_RELAXED, AGENT);
        }
    }

    for (int s = 0; s < CHUNK; ++s) {
        const int k = t0 + s;
        const unsigned short* hin = (k & 1) ? h1 : h0;
        unsigned short* hout = (k & 1) ? h0 : h1;
        const float* Gt = G + (size_t)s * Bn * 4096;

        // ================= stream A: step k =================
        float g0[4], g1[4];
        if (kh == 0) {
#pragma unroll
            for (int r = 0; r < 4; ++r) {
                g0[r] = Gt[(size_t)(rowL + r) * 4096 + gc0];
                g1[r] = Gt[(size_t)(rowL + r) * 4096 + gc1];
            }
        }
        f32x4 acc0 = (f32x4){0.f, 0.f, 0.f, 0.f};
        f32x4 acc1 = (f32x4){0.f, 0.f, 0.f, 0.f};
#pragma unroll
        for (int j = 0; j < 16; ++j) {
            union { u64 q[2]; short8 v; } ua;
            ua.q[0] = aA[j][0]; ua.q[1] = aA[j][1];
            acc0 = __builtin_amdgcn_mfma_f32_16x16x32_bf16(ua.v, breg[0][j], acc0, 0, 0, 0);
            acc1 = __builtin_amdgcn_mfma_f32_16x16x32_bf16(ua.v, breg[1][j], acc1, 0, 0, 0);
        }
        if (kh == 1) {
            *reinterpret_cast<f32x4*>(&red[rh][0][l][0]) = acc0;
            *reinterpret_cast<f32x4*>(&red[rh][1][l][0]) = acc1;
        }
        __syncthreads();
        if (kh == 0) {
            f32x4 a0 = acc0 + *reinterpret_cast<f32x4*>(&red[rh][0][l][0]);
            f32x4 a1 = acc1 + *reinterpret_cast<f32x4*>(&red[rh][1][l][0]);
#pragma unroll
            for (int r = 0; r < 4; ++r) {
                float v0 = a0[r] + g0[r];
                float v1 = a1[r] + g1[r];
                float p0 = __shfl_xor(v0, 8);
                float p1 = __shfl_xor(v1, 8);
                float iv = (l & 8) ? p0 : v0;
                float fv = (l & 8) ? v0 : p0;
                float gv = (l & 8) ? p1 : v1;
                float ov = (l & 8) ? v1 : p1;
                float cn = sigm(fv) * cA[r] + sigm(iv) * tanh_fast(gv);
                float hn = sigm(ov) * tanh_fast(cn);
                cA[r] = cn;
                unsigned hb = f2bf(hn);
                unsigned partner = (unsigned)__shfl_xor((int)hb, 1);
                if (!(l & 8) && !(l & 1)) {
                    unsigned val = (hb & 0xFFFFu) | (partner << 16);
                    __hip_atomic_store((unsigned*)(hout + (size_t)(rowL + r) * Hn + hcol),
                                       val, __ATOMIC_RELAXED, AGENT);
                }
                if (k == Tn - 1 && !(l & 8)) {
                    out_h[(rowL + r) * Hn + hcol] = hn;
                    out_c[(rowL + r) * Hn + hcol] = cn;
                }
            }
        }
        asm volatile("s_waitcnt vmcnt(0)" ::: "memory");
        __syncthreads();
        if (tid == 0)
            __hip_atomic_store(&flagsA[b * 32], (unsigned)(k + 1), __ATOMIC_RELAXED, AGENT);

        // ---- poll B(k): flagB(k) was stored ~1 A-compute ago -> usually instant ----
        if (tid < 128) {
            int guard = 0;
            while (__hip_atomic_load(&flagsB[tid * 32], __ATOMIC_RELAXED, AGENT) < (unsigned)k &&
                   guard < (1 << 14)) {
                __builtin_amdgcn_s_sleep(1);
                ++guard;
            }
        }
        __syncthreads();

        // ---- preload stream B state(k); overlapped with pollA below ----
        u64 aB[16][2];
        {
            const unsigned short* ap = hin + (size_t)(32 + arow) * Hn + kh * 512 + koff;
#pragma unroll
            for (int j = 0; j < 16; ++j) {
                aB[j][0] = __hip_atomic_load((const u64*)(ap + j * 32),     __ATOMIC_RELAXED, AGENT);
                aB[j][1] = __hip_atomic_load((const u64*)(ap + j * 32 + 4), __ATOMIC_RELAXED, AGENT);
            }
        }

        // ---- poll A(k+1): others' stores land during our A-compute skew ----
        if (tid < 128) {
            int guard = 0;
            while (__hip_atomic_load(&flagsA[tid * 32], __ATOMIC_RELAXED, AGENT) < (unsigned)(k + 1) &&
                   guard < (1 << 14)) {
                __builtin_amdgcn_s_sleep(1);
                ++guard;
            }
        }

        // ================= stream B: step k =================
        if (kh == 0) {
#pragma unroll
            for (int r = 0; r < 4; ++r) {
                g0[r] = Gt[(size_t)(32 + rowL + r) * 4096 + gc0];
                g1[r] = Gt[(size_t)(32 + rowL + r) * 4096 + gc1];
            }
        }
        acc0 = (f32x4){0.f, 0.f, 0.f, 0.f};
        acc1 = (f32x4){0.f, 0.f, 0.f, 0.f};
#pragma unroll
        for (int j = 0; j < 16; ++j) {
            union { u64 q[2]; short8 v; } ua;
            ua.q[0] = aB[j][0]; ua.q[1] = aB[j][1];
            acc0 = __builtin_amdgcn_mfma_f32_16x16x32_bf16(ua.v, breg[0][j], acc0, 0, 0, 0);
            acc1 = __builtin_amdgcn_mfma_f32_16x16x32_bf16(ua.v, breg[1][j], acc1, 0, 0, 0);
        }
        if (kh == 1) {
            *reinterpret_cast<f32x4*>(&red[rh][0][l][0]) = acc0;
            *reinterpret_cast<f32x4*>(&red[rh][1][l][0]) = acc1;
        }
        __syncthreads();   // also joins pollA for all waves
        if (kh == 0) {
            f32x4 a0 = acc0 + *reinterpret_cast<f32x4*>(&red[rh][0][l][0]);
            f32x4 a1 = acc1 + *reinterpret_cast<f32x4*>(&red[rh][1][l][0]);
#pragma unroll
            for (int r = 0; r < 4; ++r) {
                float v0 = a0[r] + g0[r];
                float v1 = a1[r] + g1[r];
                float p0 = __shfl_xor(v0, 8);
                float p1 = __shfl_xor(v1, 8);
                float iv = (l & 8) ? p0 : v0;
                float fv = (l & 8) ? v0 : p0;
                float gv = (l & 8) ? p1 : v1;
                float ov = (l & 8) ? v1 : p1;
                float cn = sigm(fv) * cB[r] + sigm(iv) * tanh_fast(gv);
                float hn = sigm(ov) * tanh_fast(cn);
                cB[r] = cn;
                unsigned hb = f2bf(hn);
                unsigned partner = (unsigned)__shfl_xor((int)hb, 1);
                if (!(l & 8) && !(l & 1)) {
                    unsigned val = (hb & 0xFFFFu) | (partner << 16);
                    __hip_atomic_store((unsigned*)(hout + (size_t)(32 + rowL + r) * Hn + hcol),
                                       val, __ATOMIC_RELAXED, AGENT);
                }
                if (k == Tn - 1 && !(l & 8)) {
                    out_h[(32 + rowL + r) * Hn + hcol] = hn;
                    out_c[(32 + rowL + r) * Hn + hcol] = cn;
                }
            }
        }
        asm volatile("s_waitcnt vmcnt(0)" ::: "memory");
        __syncthreads();
        if (tid == 0)
            __hip_atomic_store(&flagsB[b * 32], (unsigned)(k + 1), __ATOMIC_RELAXED, AGENT);

        // ---- preload stream A state(k+1) (verified by pollA above); flies
        //      across the round boundary into next round's A-MFMA ----
        if (s < CHUNK - 1) {
            const unsigned short* ap = hout + (size_t)arow * Hn + kh * 512 + koff;
#pragma unroll
            for (int j = 0; j < 16; ++j) {
                aA[j][0] = __hip_atomic_load((const u64*)(ap + j * 32),     __ATOMIC_RELAXED, AGENT);
                aA[j][1] = __hip_atomic_load((const u64*)(ap + j * 32 + 4), __ATOMIC_RELAXED, AGENT);
            }
        }
    }

    if (kh == 0 && !(l & 8)) {
#pragma unroll
        for (int r = 0; r < 4; ++r) {
            c_state[(rowL + r) * Hn + hcol] = cA[r];
            c_state[(32 + rowL + r) * Hn + hcol] = cB[r];
        }
    }
}

// ---------------- classifier: logits[64,V] = h @ W_cls^T + b ----------------
__global__ __launch_bounds__(256)
void classifier(const unsigned short* __restrict__ h,
                const float* __restrict__ Wcls, const float* __restrict__ bcls,
                float* __restrict__ logits)
{
    __shared__ __align__(16) unsigned short Al[64][72];
    __shared__ __align__(16) unsigned short Bl[64][72];

    const int tid = threadIdx.x;
    const int v0 = blockIdx.x * 64;
    const int w = tid >> 6, l = tid & 63;
    const int lrow = tid >> 2, q = tid & 3;
    const int v = v0 + lrow;

    const unsigned short* hrow = h + lrow * Hn;
    const float* wrow = Wcls + (size_t)v * Hn;

    f32x4 acc[4];
#pragma unroll
    for (int ct = 0; ct < 4; ++ct) acc[ct] = (f32x4){0.f, 0.f, 0.f, 0.f};

    const int arow = w * 16 + (l & 15);
    const int koff = (l >> 4) * 8;

    for (int ch = 0; ch < 16; ++ch) {
        const int k0 = ch * 64;
        __syncthreads();
#pragma unroll
        for (int i2 = 0; i2 < 4; ++i2) {
            const int k = q * 4 + i2 * 16;
            *reinterpret_cast<ushort4*>(&Al[lrow][k]) =
                *reinterpret_cast<const ushort4*>(hrow + k0 + k);
            if (v < Vn) {
                float4 x = *reinterpret_cast<const float4*>(wrow + k0 + k);
                Bl[lrow][k + 0] = f2bf(x.x); Bl[lrow][k + 1] = f2bf(x.y);
                Bl[lrow][k + 2] = f2bf(x.z); Bl[lrow][k + 3] = f2bf(x.w);
            } else {
                ushort4 z; z.x = z.y = z.z = z.w = 0;
                *reinterpret_cast<ushort4*>(&Bl[lrow][k]) = z;
            }
        }
        __syncthreads();

        short8 a0 = *reinterpret_cast<const short8*>(&Al[arow][koff]);
        short8 a1 = *reinterpret_cast<const short8*>(&Al[arow][32 + koff]);
#pragma unroll
        for (int ct = 0; ct < 4; ++ct) {
            const int bcol = ct * 16 + (l & 15);
            short8 b0 = *reinterpret_cast<const short8*>(&Bl[bcol][koff]);
            short8 b1 = *reinterpret_cast<const short8*>(&Bl[bcol][32 + koff]);
            acc[ct] = __builtin_amdgcn_mfma_f32_16x16x32_bf16(a0, b0, acc[ct], 0, 0, 0);
            acc[ct] = __builtin_amdgcn_mfma_f32_16x16x32_bf16(a1, b1, acc[ct], 0, 0, 0);
        }
    }

    const int rr0 = w * 16 + (l >> 4) * 4;
#pragma unroll
    for (int ct = 0; ct < 4; ++ct) {
        const int vv = v0 + ct * 16 + (l & 15);
        if (vv < Vn) {
            float bb = bcls[vv];
#pragma unroll
            for (int r = 0; r < 4; ++r)
                logits[(size_t)(rr0 + r) * Vn + vv] = acc[ct][r] + bb;
        }
    }
}

extern "C" void kernel_launch(void* const* d_in, const int* in_sizes, int n_in,
                              void* d_out, int out_size, void* d_ws, size_t ws_size,
                              hipStream_t stream)
{
    const int*   tokens = (const int*)d_in[0];
    const float* emb    = (const float*)d_in[1];
    const float* W_ih   = (const float*)d_in[2];
    const float* W_hh   = (const float*)d_in[3];
    const float* W_cls  = (const float*)d_in[4];
    const float* b_cls  = (const float*)d_in[5];
    float* out = (float*)d_out;

    // ws layout (~88.5 MB):
    // [h0 128K][h1 128K][c 256K][flagsA 16K][flagsB 16K][Wih_bf 8M][Whh_bf 8M][X 8M][G 64M]
    char* ws = (char*)d_ws;
    unsigned short* hbuf0  = (unsigned short*)ws;
    unsigned short* hbuf1  = (unsigned short*)(ws + 131072);
    float*          cst    = (float*)(ws + 262144);
    unsigned*       flagsA = (unsigned*)(ws + 524288);
    unsigned*       flagsB = (unsigned*)(ws + 540672);
    unsigned short* Wih_b  = (unsigned short*)(ws + 557056);
    unsigned short* Whh_b  = (unsigned short*)(ws + 557056 + 8388608);
    unsigned short* Xb     = (unsigned short*)(ws + 557056 + 2 * 8388608);
    float*          Gb     = (float*)(ws + 557056 + 3 * 8388608);

    // zero h(0), c(0), flags each call
    hipMemsetAsync(ws, 0, 557056, stream);

    const int n4 = (4 * Hn * En) / 4;
    cvt_f32_bf16<<<n4 / 256, 256, 0, stream>>>(W_ih, Wih_b, n4);
    cvt_f32_bf16<<<n4 / 256, 256, 0, stream>>>(W_hh, Whh_b, n4);

    float* out_h = out + (size_t)Bn * Vn;
    float* out_c = out_h + Bn * Hn;

    for (int c = 0; c < NCHUNK; ++c) {
        int t0 = c * CHUNK;
        gather_x<<<CHUNK * Bn, 256, 0, stream>>>(tokens, emb, Xb, t0);
        gemm_gin<<<32 * 32, 256, 0, stream>>>(Xb, Wih_b, Gb);
        lstm_chunk<<<128, 256, 0, stream>>>(Gb, Whh_b, hbuf0, hbuf1,
                                            cst, flagsA, flagsB, t0, out_h, out_c);
    }

    classifier<<<(Vn + 63) / 64, 256, 0, stream>>>(hbuf0, W_cls, b_cls, out);
}

// Round 8
// 4610.107 us; speedup vs baseline: 1.4372x; 1.4372x over previous
//
#include <hip/hip_runtime.h>

// Problem dims (fixed)
#define Bn 64
#define Tn 512
#define En 1024
#define Hn 1024
#define Vn 50257
#define CHUNK 64
#define NCHUNK (Tn / CHUNK)
#define AGENT __HIP_MEMORY_SCOPE_AGENT

typedef __attribute__((ext_vector_type(8))) short short8;
typedef __attribute__((ext_vector_type(4))) float f32x4;
typedef __attribute__((ext_vector_type(4))) unsigned int u32x4;
typedef unsigned long long u64;

__device__ __forceinline__ unsigned short f2bf(float f) {
    union { float f; unsigned u; } x; x.f = f;
    unsigned r = x.u + 0x7FFFu + ((x.u >> 16) & 1u);   // RNE; values are tame
    return (unsigned short)(r >> 16);
}
__device__ __forceinline__ float sigm(float x) { return 1.0f / (1.0f + __expf(-x)); }
__device__ __forceinline__ float tanh_fast(float x) {
    float e = __expf(2.0f * x);
    return (e - 1.0f) / (e + 1.0f);
}

// 16B IC-coherent load (bypasses L1/L2 caching -> coherent at Infinity Cache)
#define LDH(dst, base, IMM)                                                  \
    asm volatile("global_load_dwordx4 %0, %1, off offset:" #IMM " sc0 sc1"   \
                 : "=v"(dst) : "v"(base) : "memory")

// counted wait + scheduler fence (rule #18: MFMA must not hoist past the wait)
#define VMW(N) do { asm volatile("s_waitcnt vmcnt(" #N ")" ::: "memory");    \
                    __builtin_amdgcn_sched_barrier(0); } while (0)

// issue one group of 8 16B h-loads (2 row-tiles x 4 consecutive j)
#define ISSUE_GRP(buf, O0, O1, O2, O3)                                       \
    do {                                                                     \
        LDH((buf)[0], ap0, O0); LDH((buf)[1], ap0, O1);                      \
        LDH((buf)[2], ap0, O2); LDH((buf)[3], ap0, O3);                      \
        LDH((buf)[4], ap1, O0); LDH((buf)[5], ap1, O1);                      \
        LDH((buf)[6], ap1, O2); LDH((buf)[7], ap1, O3);                      \
    } while (0)

// consume 8 fragments (2 row-tiles x 4 j) against breg[ct][jb..jb+3]
#define MFMA_GRP(buf, jb)                                                    \
    do {                                                                     \
        _Pragma("unroll")                                                    \
        for (int jj = 0; jj < 4; ++jj) {                                     \
            union { u32x4 u; short8 s; } f0, f1;                             \
            f0.u = (buf)[jj]; f1.u = (buf)[4 + jj];                          \
            acc[0][0] = __builtin_amdgcn_mfma_f32_16x16x32_bf16(f0.s, breg[0][(jb) + jj], acc[0][0], 0, 0, 0); \
            acc[0][1] = __builtin_amdgcn_mfma_f32_16x16x32_bf16(f0.s, breg[1][(jb) + jj], acc[0][1], 0, 0, 0); \
            acc[1][0] = __builtin_amdgcn_mfma_f32_16x16x32_bf16(f1.s, breg[0][(jb) + jj], acc[1][0], 0, 0, 0); \
            acc[1][1] = __builtin_amdgcn_mfma_f32_16x16x32_bf16(f1.s, breg[1][(jb) + jj], acc[1][1], 0, 0, 0); \
        }                                                                    \
    } while (0)

// ---------------- fp32 -> bf16 weight convert ----------------
__global__ __launch_bounds__(256)
void cvt_f32_bf16(const float* __restrict__ src, unsigned short* __restrict__ dst, int n4) {
    int i = blockIdx.x * 256 + threadIdx.x;
    if (i < n4) {
        float4 v = reinterpret_cast<const float4*>(src)[i];
        ushort4 o;
        o.x = f2bf(v.x); o.y = f2bf(v.y); o.z = f2bf(v.z); o.w = f2bf(v.w);
        reinterpret_cast<ushort4*>(dst)[i] = o;
    }
}

// ---------------- embedding gather for one 64-step chunk ----------------
__global__ __launch_bounds__(256)
void gather_x(const int* __restrict__ tokens, const float* __restrict__ emb,
              unsigned short* __restrict__ X, int t0) {
    const int r = blockIdx.x;
    const int trel = r >> 6, b = r & 63;
    const int tok = tokens[b * Tn + t0 + trel];
    const float* src = emb + (size_t)tok * En;
    const int k = threadIdx.x * 4;
    float4 v = *reinterpret_cast<const float4*>(src + k);
    ushort4 o;
    o.x = f2bf(v.x); o.y = f2bf(v.y); o.z = f2bf(v.z); o.w = f2bf(v.w);
    *reinterpret_cast<ushort4*>(X + (size_t)r * En + k) = o;
}

// ---------------- G = X @ W_ih^T  (4096 x 4096, K=1024), fp32 out ----------------
__global__ __launch_bounds__(256)
void gemm_gin(const unsigned short* __restrict__ X, const unsigned short* __restrict__ Wih,
              float* __restrict__ G) {
    __shared__ __align__(16) unsigned short As[128][72];
    __shared__ __align__(16) unsigned short Bs[128][72];

    const int tid = threadIdx.x;
    const int bx = blockIdx.x & 31;
    const int by = blockIdx.x >> 5;
    const int w = tid >> 6, l = tid & 63;
    const int wr = w >> 1, wc = w & 1;

    f32x4 acc[4][4];
#pragma unroll
    for (int i = 0; i < 4; ++i)
#pragma unroll
        for (int j = 0; j < 4; ++j) acc[i][j] = (f32x4){0.f, 0.f, 0.f, 0.f};

    const int koff = (l >> 4) * 8;

    for (int kk = 0; kk < En / 64; ++kk) {
        __syncthreads();
#pragma unroll
        for (int j = 0; j < 4; ++j) {
            const int u = tid * 4 + j;
            const int row = u >> 3, ku = (u & 7) * 8;
            *reinterpret_cast<short8*>(&As[row][ku]) =
                *reinterpret_cast<const short8*>(X + (size_t)(by * 128 + row) * En + kk * 64 + ku);
            *reinterpret_cast<short8*>(&Bs[row][ku]) =
                *reinterpret_cast<const short8*>(Wih + (size_t)(bx * 128 + row) * En + kk * 64 + ku);
        }
        __syncthreads();

#pragma unroll
        for (int kc = 0; kc < 2; ++kc) {
            const int k0 = kc * 32 + koff;
            short8 af[4], bf[4];
#pragma unroll
            for (int i = 0; i < 4; ++i)
                af[i] = *reinterpret_cast<const short8*>(&As[wr * 64 + i * 16 + (l & 15)][k0]);
#pragma unroll
            for (int j = 0; j < 4; ++j)
                bf[j] = *reinterpret_cast<const short8*>(&Bs[wc * 64 + j * 16 + (l & 15)][k0]);
#pragma unroll
            for (int i = 0; i < 4; ++i)
#pragma unroll
                for (int j = 0; j < 4; ++j)
                    acc[i][j] = __builtin_amdgcn_mfma_f32_16x16x32_bf16(af[i], bf[j], acc[i][j], 0, 0, 0);
        }
    }

    const int rr = 4 * (l >> 4);
#pragma unroll
    for (int i = 0; i < 4; ++i) {
        const int row = by * 128 + wr * 64 + i * 16 + rr;
#pragma unroll
        for (int j = 0; j < 4; ++j) {
            const int col = bx * 128 + wc * 64 + j * 16 + (l & 15);
#pragma unroll
            for (int r = 0; r < 4; ++r)
                G[(size_t)(row + r) * 4096 + col] = acc[i][j][r];
        }
    }
}

// ---------------- persistent recurrent kernel ----------
// 128 blocks x 256 threads, 1 block/CU, launch_bounds(256,1) -> ~512 VGPR
// budget so breg(128) + 4 load buffers(128) stay simultaneously live.
// Block b owns 32 gate-cols (tile0=[i|f] x 8 hcols, tile1=[g|o] x 8 hcols).
// Wave (rh=w>>1, kh=w&1): rows rh*32..+31 (2 row-tiles), K-half kh.
// h read via 32x16B sc0+sc1 asm loads, counted-vmcnt 4-group pipeline:
//   issue A,B,C,D -> vmcnt(24) mfma(A) -> vmcnt(16) mfma(B)
//                 -> vmcnt(8) mfma(C) -> vmcnt(0) mfma(D).
// Wait counts are correct for kh=0 (8 extra G loads in flight) AND kh=1:
// buf X's last load sits at issue position <= 8*(X+1)+8, so it is retired
// by the wait leaving 8*(3-X) outstanding, wherever the G loads landed.
// h written via agent-scope 4B atomic stores; flag-array barrier.
__global__ __launch_bounds__(256, 1)
void lstm_chunk(const float* __restrict__ G, const unsigned short* __restrict__ Whh,
                unsigned short* __restrict__ h0, unsigned short* __restrict__ h1,
                float* __restrict__ c_state, unsigned* __restrict__ flags, int t0,
                float* __restrict__ out_h, float* __restrict__ out_c)
{
    __shared__ __align__(16) float red[2][2][2][64][4];   // [rh][rt][ct][lane][r] 16KB

    const int tid = threadIdx.x;
    const int b = blockIdx.x;
    const int w = tid >> 6, l = tid & 63;
    const int kh = w & 1, rh = w >> 1;
    const int koff = (l >> 4) * 8;
    const int lc = l & 15;
    const int hcol = b * 8 + (l & 7);

    // ---- W_hh fragments -> registers (once per launch) ----
    short8 breg[2][16];
#pragma unroll
    for (int ct = 0; ct < 2; ++ct) {
        const int gate = ct * 2 + (lc >> 3);
        const unsigned short* wrow = Whh + ((size_t)gate * Hn + (b * 8 + (lc & 7))) * Hn;
#pragma unroll
        for (int j = 0; j < 16; ++j)
            breg[ct][j] = *reinterpret_cast<const short8*>(wrow + (kh * 16 + j) * 32 + koff);
    }

    // ---- c-state in registers (kh==0 waves own the cell update) ----
    float c_reg[2][4];
    if (kh == 0) {
#pragma unroll
        for (int rt = 0; rt < 2; ++rt)
#pragma unroll
            for (int r = 0; r < 4; ++r)
                c_reg[rt][r] = c_state[(rh * 32 + rt * 16 + ((l >> 4) << 2) + r) * Hn + hcol];
    }

    const int sg = lc >> 3;
    const int gc0 = sg * Hn + hcol;          // i (sg=0) / f (sg=1)
    const int gc1 = (2 + sg) * Hn + hcol;    // g / o

    for (int s = 0; s < CHUNK; ++s) {
        const int t = t0 + s;
        const unsigned short* hin = (t & 1) ? h1 : h0;
        unsigned short* hout = (t & 1) ? h0 : h1;

        // ---- G loads (plain; compiler-scheduled anywhere in the issue
        //      window -- wait counts are placement-independent, see header) ----
        float g0[2][4], g1[2][4];
        if (kh == 0) {
            const float* Gt = G + (size_t)s * Bn * 4096;
#pragma unroll
            for (int rt = 0; rt < 2; ++rt) {
                const int rowbase = rh * 32 + rt * 16 + ((l >> 4) << 2);
#pragma unroll
                for (int r = 0; r < 4; ++r) {
                    g0[rt][r] = Gt[(size_t)(rowbase + r) * 4096 + gc0];
                    g1[rt][r] = Gt[(size_t)(rowbase + r) * 4096 + gc1];
                }
            }
        }

        const unsigned short* ap0 =
            hin + (size_t)(rh * 32 + (l & 15)) * Hn + kh * 512 + koff;
        const unsigned short* ap1 =
            hin + (size_t)(rh * 32 + 16 + (l & 15)) * Hn + kh * 512 + koff;

        f32x4 acc[2][2];
        acc[0][0] = acc[0][1] = acc[1][0] = acc[1][1] = (f32x4){0.f, 0.f, 0.f, 0.f};

        u32x4 bufA[8], bufB[8], bufC[8], bufD[8];
        ISSUE_GRP(bufA, 0,   64,  128, 192);   // j = 0..3
        ISSUE_GRP(bufB, 256, 320, 384, 448);   // j = 4..7
        ISSUE_GRP(bufC, 512, 576, 640, 704);   // j = 8..11
        ISSUE_GRP(bufD, 768, 832, 896, 960);   // j = 12..15

        VMW(24); MFMA_GRP(bufA, 0);
        VMW(16); MFMA_GRP(bufB, 4);
        VMW(8);  MFMA_GRP(bufC, 8);
        VMW(0);  MFMA_GRP(bufD, 12);

        // ---- K-split reduction via LDS ----
        if (kh == 1) {
#pragma unroll
            for (int rt = 0; rt < 2; ++rt)
#pragma unroll
                for (int ct = 0; ct < 2; ++ct)
                    *reinterpret_cast<f32x4*>(&red[rh][rt][ct][l][0]) = acc[rt][ct];
        }
        __syncthreads();

        if (kh == 0) {
#pragma unroll
            for (int rt = 0; rt < 2; ++rt) {
                const int rowbase = rh * 32 + rt * 16 + ((l >> 4) << 2);
                f32x4 a0 = acc[rt][0] + *reinterpret_cast<f32x4*>(&red[rh][rt][0][l][0]);
                f32x4 a1 = acc[rt][1] + *reinterpret_cast<f32x4*>(&red[rh][rt][1][l][0]);
#pragma unroll
                for (int r = 0; r < 4; ++r) {
                    float v0 = a0[r] + g0[rt][r];
                    float v1 = a1[r] + g1[rt][r];
                    float p0 = __shfl_xor(v0, 8);
                    float p1 = __shfl_xor(v1, 8);
                    float iv = (l & 8) ? p0 : v0;
                    float fv = (l & 8) ? v0 : p0;
                    float gv = (l & 8) ? p1 : v1;
                    float ov = (l & 8) ? v1 : p1;
                    float cn = sigm(fv) * c_reg[rt][r] + sigm(iv) * tanh_fast(gv);
                    float hn = sigm(ov) * tanh_fast(cn);
                    c_reg[rt][r] = cn;
                    unsigned hb = f2bf(hn);
                    unsigned partner = (unsigned)__shfl_xor((int)hb, 1);
                    if (!(l & 8) && !(l & 1)) {
                        unsigned val = (hb & 0xFFFFu) | (partner << 16);
                        __hip_atomic_store(
                            (unsigned*)(hout + (size_t)(rowbase + r) * Hn + hcol),
                            val, __ATOMIC_RELAXED, AGENT);
                    }
                    if (t == Tn - 1 && !(l & 8)) {
                        out_h[(rowbase + r) * Hn + hcol] = hn;
                        out_c[(rowbase + r) * Hn + hcol] = cn;
                    }
                }
            }
        }

        // ---- flag-array barrier ----
        asm volatile("s_waitcnt vmcnt(0)" ::: "memory");
        __syncthreads();
        if (tid == 0)
            __hip_atomic_store(&flags[b * 32], (unsigned)(t + 1), __ATOMIC_RELAXED, AGENT);
        if (tid < 128) {
            const unsigned target = (unsigned)(t + 1);
            int guard = 0;
            while (__hip_atomic_load(&flags[tid * 32], __ATOMIC_RELAXED, AGENT) < target &&
                   guard < (1 << 16)) {
                __builtin_amdgcn_s_sleep(1);
                ++guard;
            }
        }
        __syncthreads();
    }

    if (kh == 0 && !(l & 8)) {
#pragma unroll
        for (int rt = 0; rt < 2; ++rt)
#pragma unroll
            for (int r = 0; r < 4; ++r)
                c_state[(rh * 32 + rt * 16 + ((l >> 4) << 2) + r) * Hn + hcol] = c_reg[rt][r];
    }
}

// ---------------- classifier: logits[64,V] = h @ W_cls^T + b ----------------
__global__ __launch_bounds__(256)
void classifier(const unsigned short* __restrict__ h,
                const float* __restrict__ Wcls, const float* __restrict__ bcls,
                float* __restrict__ logits)
{
    __shared__ __align__(16) unsigned short Al[64][72];
    __shared__ __align__(16) unsigned short Bl[64][72];

    const int tid = threadIdx.x;
    const int v0 = blockIdx.x * 64;
    const int w = tid >> 6, l = tid & 63;
    const int lrow = tid >> 2, q = tid & 3;
    const int v = v0 + lrow;

    const unsigned short* hrow = h + lrow * Hn;
    const float* wrow = Wcls + (size_t)v * Hn;

    f32x4 acc[4];
#pragma unroll
    for (int ct = 0; ct < 4; ++ct) acc[ct] = (f32x4){0.f, 0.f, 0.f, 0.f};

    const int arow = w * 16 + (l & 15);
    const int koff = (l >> 4) * 8;

    for (int ch = 0; ch < 16; ++ch) {
        const int k0 = ch * 64;
        __syncthreads();
#pragma unroll
        for (int i2 = 0; i2 < 4; ++i2) {
            const int k = q * 4 + i2 * 16;
            *reinterpret_cast<ushort4*>(&Al[lrow][k]) =
                *reinterpret_cast<const ushort4*>(hrow + k0 + k);
            if (v < Vn) {
                float4 x = *reinterpret_cast<const float4*>(wrow + k0 + k);
                Bl[lrow][k + 0] = f2bf(x.x); Bl[lrow][k + 1] = f2bf(x.y);
                Bl[lrow][k + 2] = f2bf(x.z); Bl[lrow][k + 3] = f2bf(x.w);
            } else {
                ushort4 z; z.x = z.y = z.z = z.w = 0;
                *reinterpret_cast<ushort4*>(&Bl[lrow][k]) = z;
            }
        }
        __syncthreads();

        short8 a0 = *reinterpret_cast<const short8*>(&Al[arow][koff]);
        short8 a1 = *reinterpret_cast<const short8*>(&Al[arow][32 + koff]);
#pragma unroll
        for (int ct = 0; ct < 4; ++ct) {
            const int bcol = ct * 16 + (l & 15);
            short8 b0 = *reinterpret_cast<const short8*>(&Bl[bcol][koff]);
            short8 b1 = *reinterpret_cast<const short8*>(&Bl[bcol][32 + koff]);
            acc[ct] = __builtin_amdgcn_mfma_f32_16x16x32_bf16(a0, b0, acc[ct], 0, 0, 0);
            acc[ct] = __builtin_amdgcn_mfma_f32_16x16x32_bf16(a1, b1, acc[ct], 0, 0, 0);
        }
    }

    const int rr0 = w * 16 + (l >> 4) * 4;
#pragma unroll
    for (int ct = 0; ct < 4; ++ct) {
        const int vv = v0 + ct * 16 + (l & 15);
        if (vv < Vn) {
            float bb = bcls[vv];
#pragma unroll
            for (int r = 0; r < 4; ++r)
                logits[(size_t)(rr0 + r) * Vn + vv] = acc[ct][r] + bb;
        }
    }
}

extern "C" void kernel_launch(void* const* d_in, const int* in_sizes, int n_in,
                              void* d_out, int out_size, void* d_ws, size_t ws_size,
                              hipStream_t stream)
{
    const int*   tokens = (const int*)d_in[0];
    const float* emb    = (const float*)d_in[1];
    const float* W_ih   = (const float*)d_in[2];
    const float* W_hh   = (const float*)d_in[3];
    const float* W_cls  = (const float*)d_in[4];
    const float* b_cls  = (const float*)d_in[5];
    float* out = (float*)d_out;

    // ws layout (~88.5 MB):
    // [h0 128K][h1 128K][c 256K][flags 16K][Wih_bf 8M][Whh_bf 8M][X 8M][G 64M]
    char* ws = (char*)d_ws;
    unsigned short* hbuf0 = (unsigned short*)ws;
    unsigned short* hbuf1 = (unsigned short*)(ws + 131072);
    float*          cst   = (float*)(ws + 262144);
    unsigned*       flags = (unsigned*)(ws + 524288);
    unsigned short* Wih_b = (unsigned short*)(ws + 540672);
    unsigned short* Whh_b = (unsigned short*)(ws + 540672 + 8388608);
    unsigned short* Xb    = (unsigned short*)(ws + 540672 + 2 * 8388608);
    float*          Gb    = (float*)(ws + 540672 + 3 * 8388608);

    // zero h(0), c(0), flags each call
    hipMemsetAsync(ws, 0, 540672, stream);

    const int n4 = (4 * Hn * En) / 4;
    cvt_f32_bf16<<<n4 / 256, 256, 0, stream>>>(W_ih, Wih_b, n4);
    cvt_f32_bf16<<<n4 / 256, 256, 0, stream>>>(W_hh, Whh_b, n4);

    float* out_h = out + (size_t)Bn * Vn;
    float* out_c = out_h + Bn * Hn;

    for (int c = 0; c < NCHUNK; ++c) {
        int t0 = c * CHUNK;
        gather_x<<<CHUNK * Bn, 256, 0, stream>>>(tokens, emb, Xb, t0);
        gemm_gin<<<32 * 32, 256, 0, stream>>>(Xb, Wih_b, Gb);
        lstm_chunk<<<128, 256, 0, stream>>>(Gb, Whh_b, hbuf0, hbuf1,
                                            cst, flags, t0, out_h, out_c);
    }

    classifier<<<(Vn + 63) / 64, 256, 0, stream>>>(hbuf0, W_cls, b_cls, out);
}

// Round 9
// 4286.883 us; speedup vs baseline: 1.5455x; 1.0754x over previous
//
#include <hip/hip_runtime.h>

// Problem dims (fixed)
#define Bn 64
#define Tn 512
#define En 1024
#define Hn 1024
#define Vn 50257
#define CHUNK 64
#define NCHUNK (Tn / CHUNK)
#define AGENT __HIP_MEMORY_SCOPE_AGENT

typedef __attribute__((ext_vector_type(8))) short short8;
typedef __attribute__((ext_vector_type(4))) float f32x4;
typedef __attribute__((ext_vector_type(4))) unsigned int u32x4;

__device__ __forceinline__ unsigned short f2bf(float f) {
    union { float f; unsigned u; } x; x.f = f;
    unsigned r = x.u + 0x7FFFu + ((x.u >> 16) & 1u);   // RNE; values are tame
    return (unsigned short)(r >> 16);
}
__device__ __forceinline__ float bf2f(unsigned short u) {
    union { unsigned u; float f; } x; x.u = ((unsigned)u) << 16; return x.f;
}
__device__ __forceinline__ float sigm(float x) { return 1.0f / (1.0f + __expf(-x)); }
__device__ __forceinline__ float tanh_fast(float x) {
    float e = __expf(2.0f * x);
    return (e - 1.0f) / (e + 1.0f);
}

// 16B IC-coherent load (bypasses L1/L2 -> coherent at Infinity Cache)
#define LDH(dst, base, IMM)                                                  \
    asm volatile("global_load_dwordx4 %0, %1, off offset:" #IMM " sc0 sc1"   \
                 : "=v"(dst) : "v"(base) : "memory")
// counted wait + scheduler fence (rule #18)
#define VMW(N) do { asm volatile("s_waitcnt vmcnt(" #N ")" ::: "memory");    \
                    __builtin_amdgcn_sched_barrier(0); } while (0)
// issue one group of 8 16B h-loads (2 row-tiles x 4 consecutive j)
#define ISSUE_GRP(buf, O0, O1, O2, O3)                                       \
    do {                                                                     \
        LDH((buf)[0], ap0, O0); LDH((buf)[1], ap0, O1);                      \
        LDH((buf)[2], ap0, O2); LDH((buf)[3], ap0, O3);                      \
        LDH((buf)[4], ap1, O0); LDH((buf)[5], ap1, O1);                      \
        LDH((buf)[6], ap1, O2); LDH((buf)[7], ap1, O3);                      \
    } while (0)
// consume 8 fragments against breg[ct][jb..jb+3]
#define MFMA_GRP(buf, jb)                                                    \
    do {                                                                     \
        _Pragma("unroll")                                                    \
        for (int jj = 0; jj < 4; ++jj) {                                     \
            union { u32x4 u; short8 s; } f0, f1;                             \
            f0.u = (buf)[jj]; f1.u = (buf)[4 + jj];                          \
            acc[0][0] = __builtin_amdgcn_mfma_f32_16x16x32_bf16(f0.s, breg[0][(jb) + jj], acc[0][0], 0, 0, 0); \
            acc[0][1] = __builtin_amdgcn_mfma_f32_16x16x32_bf16(f0.s, breg[1][(jb) + jj], acc[0][1], 0, 0, 0); \
            acc[1][0] = __builtin_amdgcn_mfma_f32_16x16x32_bf16(f1.s, breg[0][(jb) + jj], acc[1][0], 0, 0, 0); \
            acc[1][1] = __builtin_amdgcn_mfma_f32_16x16x32_bf16(f1.s, breg[1][(jb) + jj], acc[1][1], 0, 0, 0); \
        }                                                                    \
    } while (0)

// ---------------- fp32 -> bf16 weight convert ----------------
__global__ __launch_bounds__(256)
void cvt_f32_bf16(const float* __restrict__ src, unsigned short* __restrict__ dst, int n4) {
    int i = blockIdx.x * 256 + threadIdx.x;
    if (i < n4) {
        float4 v = reinterpret_cast<const float4*>(src)[i];
        ushort4 o;
        o.x = f2bf(v.x); o.y = f2bf(v.y); o.z = f2bf(v.z); o.w = f2bf(v.w);
        reinterpret_cast<ushort4*>(dst)[i] = o;
    }
}

// ---------------- embedding gather for one 64-step chunk ----------------
__global__ __launch_bounds__(256)
void gather_x(const int* __restrict__ tokens, const float* __restrict__ emb,
              unsigned short* __restrict__ X, int t0) {
    const int r = blockIdx.x;
    const int trel = r >> 6, b = r & 63;
    const int tok = tokens[b * Tn + t0 + trel];
    const float* src = emb + (size_t)tok * En;
    const int k = threadIdx.x * 4;
    float4 v = *reinterpret_cast<const float4*>(src + k);
    ushort4 o;
    o.x = f2bf(v.x); o.y = f2bf(v.y); o.z = f2bf(v.z); o.w = f2bf(v.w);
    *reinterpret_cast<ushort4*>(X + (size_t)r * En + k) = o;
}

// ---- shared gemm tile body: computes one 128x128 tile of X @ Wih^T (bf16 out) ----
__device__ __forceinline__ void gemm_tile(
    const unsigned short* __restrict__ X, const unsigned short* __restrict__ Wih,
    unsigned short* __restrict__ G, int bx, int by,
    unsigned short (*As)[72], unsigned short (*Bs)[72], int tid)
{
    const int w = tid >> 6, l = tid & 63;
    const int wr = w >> 1, wc = w & 1;
    const int koff = (l >> 4) * 8;

    f32x4 acc[4][4];
#pragma unroll
    for (int i = 0; i < 4; ++i)
#pragma unroll
        for (int j = 0; j < 4; ++j) acc[i][j] = (f32x4){0.f, 0.f, 0.f, 0.f};

    for (int kk = 0; kk < En / 64; ++kk) {
        __syncthreads();
#pragma unroll
        for (int j = 0; j < 4; ++j) {
            const int u = tid * 4 + j;
            const int row = u >> 3, ku = (u & 7) * 8;
            *reinterpret_cast<short8*>(&As[row][ku]) =
                *reinterpret_cast<const short8*>(X + (size_t)(by * 128 + row) * En + kk * 64 + ku);
            *reinterpret_cast<short8*>(&Bs[row][ku]) =
                *reinterpret_cast<const short8*>(Wih + (size_t)(bx * 128 + row) * En + kk * 64 + ku);
        }
        __syncthreads();

#pragma unroll
        for (int kc = 0; kc < 2; ++kc) {
            const int k0 = kc * 32 + koff;
            short8 af[4], bf[4];
#pragma unroll
            for (int i = 0; i < 4; ++i)
                af[i] = *reinterpret_cast<const short8*>(&As[wr * 64 + i * 16 + (l & 15)][k0]);
#pragma unroll
            for (int j = 0; j < 4; ++j)
                bf[j] = *reinterpret_cast<const short8*>(&Bs[wc * 64 + j * 16 + (l & 15)][k0]);
#pragma unroll
            for (int i = 0; i < 4; ++i)
#pragma unroll
                for (int j = 0; j < 4; ++j)
                    acc[i][j] = __builtin_amdgcn_mfma_f32_16x16x32_bf16(af[i], bf[j], acc[i][j], 0, 0, 0);
        }
    }

    const int rr = 4 * (l >> 4);
#pragma unroll
    for (int i = 0; i < 4; ++i) {
        const int row = by * 128 + wr * 64 + i * 16 + rr;
#pragma unroll
        for (int j = 0; j < 4; ++j) {
            const int col = bx * 128 + wc * 64 + j * 16 + (l & 15);
#pragma unroll
            for (int r = 0; r < 4; ++r)
                G[(size_t)(row + r) * 4096 + col] = f2bf(acc[i][j][r]);
        }
    }
}

// ---------------- standalone G = X @ W_ih^T (chunk 0 only), bf16 out ----------------
__global__ __launch_bounds__(256)
void gemm_gin(const unsigned short* __restrict__ X, const unsigned short* __restrict__ Wih,
              unsigned short* __restrict__ G) {
    __shared__ __align__(16) unsigned short As[128][72];
    __shared__ __align__(16) unsigned short Bs[128][72];
    gemm_tile(X, Wih, G, blockIdx.x & 31, blockIdx.x >> 5, As, Bs, threadIdx.x);
}

// ---------------- fused: recurrence (blocks 0-127) + next-chunk GEMM (128-255) ----
// Recurrence identical to r8 except: G is bf16, and G(s+1) is prefetched after
// the flag store so its HBM latency hides under the barrier poll. All 256
// threads poll (tid&127) so every wave's vmem queue drains to 0 before the
// next counted-vmcnt window (keeps VMW(24/16/8/0) exact and kh-uniform).
__global__ __launch_bounds__(256, 1)
void lstm_fused(const unsigned short* __restrict__ Gcur, unsigned short* __restrict__ Gnext,
                const unsigned short* __restrict__ Xnext, const unsigned short* __restrict__ Wih,
                const unsigned short* __restrict__ Whh,
                unsigned short* __restrict__ h0, unsigned short* __restrict__ h1,
                float* __restrict__ c_state, unsigned* __restrict__ flags, int t0, int do_gemm,
                float* __restrict__ out_h, float* __restrict__ out_c)
{
    __shared__ __align__(16) char smem[2 * 128 * 72 * 2];   // 36 KB (gemm As/Bs; recurrence uses 16 KB as red)

    const int tid = threadIdx.x;

    if (blockIdx.x >= 128) {
        // ---- GEMM half: 8 tiles of G(next chunk); no barrier participation ----
        if (!do_gemm) return;
        unsigned short (*As)[72] = reinterpret_cast<unsigned short(*)[72]>(smem);
        unsigned short (*Bs)[72] = reinterpret_cast<unsigned short(*)[72]>(smem + 128 * 72 * 2);
        const int base = (blockIdx.x - 128) * 8;
        for (int tt = 0; tt < 8; ++tt) {
            const int tile = base + tt;
            gemm_tile(Xnext, Wih, Gnext, tile & 31, tile >> 5, As, Bs, tid);
        }
        return;
    }

    // ---- recurrence half ----
    typedef float RedT[2][2][64][4];                 // [rt][ct][lane][r]
    RedT* red = reinterpret_cast<RedT*>(smem);       // red[rh][rt][ct][l][r], 16 KB

    const int b = blockIdx.x;
    const int w = tid >> 6, l = tid & 63;
    const int kh = w & 1, rh = w >> 1;
    const int koff = (l >> 4) * 8;
    const int lc = l & 15;
    const int hcol = b * 8 + (l & 7);

    // W_hh fragments -> registers (once per launch)
    short8 breg[2][16];
#pragma unroll
    for (int ct = 0; ct < 2; ++ct) {
        const int gate = ct * 2 + (lc >> 3);
        const unsigned short* wrow = Whh + ((size_t)gate * Hn + (b * 8 + (lc & 7))) * Hn;
#pragma unroll
        for (int j = 0; j < 16; ++j)
            breg[ct][j] = *reinterpret_cast<const short8*>(wrow + (kh * 16 + j) * 32 + koff);
    }

    // c-state in registers (kh==0 waves own the cell update)
    float c_reg[2][4];
    if (kh == 0) {
#pragma unroll
        for (int rt = 0; rt < 2; ++rt)
#pragma unroll
            for (int r = 0; r < 4; ++r)
                c_reg[rt][r] = c_state[(rh * 32 + rt * 16 + ((l >> 4) << 2) + r) * Hn + hcol];
    }

    const int sg = lc >> 3;
    const int gc0 = sg * Hn + hcol;          // i (sg=0) / f (sg=1)
    const int gc1 = (2 + sg) * Hn + hcol;    // g / o

    // prologue: prefetch G(s=0), bf16
    unsigned short gp0[2][4], gp1[2][4];
    if (kh == 0) {
#pragma unroll
        for (int rt = 0; rt < 2; ++rt) {
            const int rowbase = rh * 32 + rt * 16 + ((l >> 4) << 2);
#pragma unroll
            for (int r = 0; r < 4; ++r) {
                gp0[rt][r] = Gcur[(size_t)(rowbase + r) * 4096 + gc0];
                gp1[rt][r] = Gcur[(size_t)(rowbase + r) * 4096 + gc1];
            }
        }
    }

    for (int s = 0; s < CHUNK; ++s) {
        const int t = t0 + s;
        const unsigned short* hin = (t & 1) ? h1 : h0;
        unsigned short* hout = (t & 1) ? h0 : h1;

        const unsigned short* ap0 =
            hin + (size_t)(rh * 32 + (l & 15)) * Hn + kh * 512 + koff;
        const unsigned short* ap1 =
            hin + (size_t)(rh * 32 + 16 + (l & 15)) * Hn + kh * 512 + koff;

        f32x4 acc[2][2];
        acc[0][0] = acc[0][1] = acc[1][0] = acc[1][1] = (f32x4){0.f, 0.f, 0.f, 0.f};

        u32x4 bufA[8], bufB[8], bufC[8], bufD[8];
        ISSUE_GRP(bufA, 0,   64,  128, 192);   // j = 0..3
        ISSUE_GRP(bufB, 256, 320, 384, 448);   // j = 4..7
        ISSUE_GRP(bufC, 512, 576, 640, 704);   // j = 8..11
        ISSUE_GRP(bufD, 768, 832, 896, 960);   // j = 12..15

        VMW(24); MFMA_GRP(bufA, 0);
        VMW(16); MFMA_GRP(bufB, 4);
        VMW(8);  MFMA_GRP(bufC, 8);
        VMW(0);  MFMA_GRP(bufD, 12);

        // K-split reduction via LDS
        if (kh == 1) {
#pragma unroll
            for (int rt = 0; rt < 2; ++rt)
#pragma unroll
                for (int ct = 0; ct < 2; ++ct)
                    *reinterpret_cast<f32x4*>(&red[rh][rt][ct][l][0]) = acc[rt][ct];
        }
        __syncthreads();

        if (kh == 0) {
#pragma unroll
            for (int rt = 0; rt < 2; ++rt) {
                const int rowbase = rh * 32 + rt * 16 + ((l >> 4) << 2);
                f32x4 a0 = acc[rt][0] + *reinterpret_cast<f32x4*>(&red[rh][rt][0][l][0]);
                f32x4 a1 = acc[rt][1] + *reinterpret_cast<f32x4*>(&red[rh][rt][1][l][0]);
#pragma unroll
                for (int r = 0; r < 4; ++r) {
                    float v0 = a0[r] + bf2f(gp0[rt][r]);
                    float v1 = a1[r] + bf2f(gp1[rt][r]);
                    float p0 = __shfl_xor(v0, 8);
                    float p1 = __shfl_xor(v1, 8);
                    float iv = (l & 8) ? p0 : v0;
                    float fv = (l & 8) ? v0 : p0;
                    float gv = (l & 8) ? p1 : v1;
                    float ov = (l & 8) ? v1 : p1;
                    float cn = sigm(fv) * c_reg[rt][r] + sigm(iv) * tanh_fast(gv);
                    float hn = sigm(ov) * tanh_fast(cn);
                    c_reg[rt][r] = cn;
                    unsigned hb = f2bf(hn);
                    unsigned partner = (unsigned)__shfl_xor((int)hb, 1);
                    if (!(l & 8) && !(l & 1)) {
                        unsigned val = (hb & 0xFFFFu) | (partner << 16);
                        __hip_atomic_store(
                            (unsigned*)(hout + (size_t)(rowbase + r) * Hn + hcol),
                            val, __ATOMIC_RELAXED, AGENT);
                    }
                    if (t == Tn - 1 && !(l & 8)) {
                        out_h[(rowbase + r) * Hn + hcol] = hn;
                        out_c[(rowbase + r) * Hn + hcol] = cn;
                    }
                }
            }
        }

        // drain h stores, arrive
        asm volatile("s_waitcnt vmcnt(0)" ::: "memory");
        __syncthreads();
        if (tid == 0)
            __hip_atomic_store(&flags[b * 32], (unsigned)(t + 1), __ATOMIC_RELAXED, AGENT);

        // prefetch G(s+1): HBM latency hides under the poll below
        if (kh == 0 && s + 1 < CHUNK) {
            const unsigned short* Gt = Gcur + (size_t)(s + 1) * Bn * 4096;
#pragma unroll
            for (int rt = 0; rt < 2; ++rt) {
                const int rowbase = rh * 32 + rt * 16 + ((l >> 4) << 2);
#pragma unroll
                for (int r = 0; r < 4; ++r) {
                    gp0[rt][r] = Gt[(size_t)(rowbase + r) * 4096 + gc0];
                    gp1[rt][r] = Gt[(size_t)(rowbase + r) * 4096 + gc1];
                }
            }
        }

        // flag-array barrier: ALL threads poll (drains every wave's vmem queue)
        {
            const unsigned target = (unsigned)(t + 1);
            const int pf = (tid & 127) * 32;
            int guard = 0;
            while (__hip_atomic_load(&flags[pf], __ATOMIC_RELAXED, AGENT) < target &&
                   guard < (1 << 16)) {
                __builtin_amdgcn_s_sleep(1);
                ++guard;
            }
        }
        __syncthreads();
    }

    if (kh == 0 && !(l & 8)) {
#pragma unroll
        for (int rt = 0; rt < 2; ++rt)
#pragma unroll
            for (int r = 0; r < 4; ++r)
                c_state[(rh * 32 + rt * 16 + ((l >> 4) << 2) + r) * Hn + hcol] = c_reg[rt][r];
    }
}

// ---------------- classifier: logits[64,V] = h @ W_cls^T + b ----------------
__global__ __launch_bounds__(256)
void classifier(const unsigned short* __restrict__ h,
                const float* __restrict__ Wcls, const float* __restrict__ bcls,
                float* __restrict__ logits)
{
    __shared__ __align__(16) unsigned short Al[64][72];
    __shared__ __align__(16) unsigned short Bl[64][72];

    const int tid = threadIdx.x;
    const int v0 = blockIdx.x * 64;
    const int w = tid >> 6, l = tid & 63;
    const int lrow = tid >> 2, q = tid & 3;
    const int v = v0 + lrow;

    const unsigned short* hrow = h + lrow * Hn;
    const float* wrow = Wcls + (size_t)v * Hn;

    f32x4 acc[4];
#pragma unroll
    for (int ct = 0; ct < 4; ++ct) acc[ct] = (f32x4){0.f, 0.f, 0.f, 0.f};

    const int arow = w * 16 + (l & 15);
    const int koff = (l >> 4) * 8;

    for (int ch = 0; ch < 16; ++ch) {
        const int k0 = ch * 64;
        __syncthreads();
#pragma unroll
        for (int i2 = 0; i2 < 4; ++i2) {
            const int k = q * 4 + i2 * 16;
            *reinterpret_cast<ushort4*>(&Al[lrow][k]) =
                *reinterpret_cast<const ushort4*>(hrow + k0 + k);
            if (v < Vn) {
                float4 x = *reinterpret_cast<const float4*>(wrow + k0 + k);
                Bl[lrow][k + 0] = f2bf(x.x); Bl[lrow][k + 1] = f2bf(x.y);
                Bl[lrow][k + 2] = f2bf(x.z); Bl[lrow][k + 3] = f2bf(x.w);
            } else {
                ushort4 z; z.x = z.y = z.z = z.w = 0;
                *reinterpret_cast<ushort4*>(&Bl[lrow][k]) = z;
            }
        }
        __syncthreads();

        short8 a0 = *reinterpret_cast<const short8*>(&Al[arow][koff]);
        short8 a1 = *reinterpret_cast<const short8*>(&Al[arow][32 + koff]);
#pragma unroll
        for (int ct = 0; ct < 4; ++ct) {
            const int bcol = ct * 16 + (l & 15);
            short8 b0 = *reinterpret_cast<const short8*>(&Bl[bcol][koff]);
            short8 b1 = *reinterpret_cast<const short8*>(&Bl[bcol][32 + koff]);
            acc[ct] = __builtin_amdgcn_mfma_f32_16x16x32_bf16(a0, b0, acc[ct], 0, 0, 0);
            acc[ct] = __builtin_amdgcn_mfma_f32_16x16x32_bf16(a1, b1, acc[ct], 0, 0, 0);
        }
    }

    const int rr0 = w * 16 + (l >> 4) * 4;
#pragma unroll
    for (int ct = 0; ct < 4; ++ct) {
        const int vv = v0 + ct * 16 + (l & 15);
        if (vv < Vn) {
            float bb = bcls[vv];
#pragma unroll
            for (int r = 0; r < 4; ++r)
                logits[(size_t)(rr0 + r) * Vn + vv] = acc[ct][r] + bb;
        }
    }
}

extern "C" void kernel_launch(void* const* d_in, const int* in_sizes, int n_in,
                              void* d_out, int out_size, void* d_ws, size_t ws_size,
                              hipStream_t stream)
{
    const int*   tokens = (const int*)d_in[0];
    const float* emb    = (const float*)d_in[1];
    const float* W_ih   = (const float*)d_in[2];
    const float* W_hh   = (const float*)d_in[3];
    const float* W_cls  = (const float*)d_in[4];
    const float* b_cls  = (const float*)d_in[5];
    float* out = (float*)d_out;

    // ws layout (~88.5 MB):
    // [h0 128K][h1 128K][c 256K][flags 16K][Wih 8M][Whh 8M][X 8M][G0 32M][G1 32M]
    char* ws = (char*)d_ws;
    unsigned short* hbuf0 = (unsigned short*)ws;
    unsigned short* hbuf1 = (unsigned short*)(ws + 131072);
    float*          cst   = (float*)(ws + 262144);
    unsigned*       flags = (unsigned*)(ws + 524288);
    unsigned short* Wih_b = (unsigned short*)(ws + 540672);
    unsigned short* Whh_b = (unsigned short*)(ws + 540672 + 8388608);
    unsigned short* Xb    = (unsigned short*)(ws + 540672 + 2 * 8388608);
    unsigned short* Gb0   = (unsigned short*)(ws + 540672 + 3 * 8388608);
    unsigned short* Gb1   = (unsigned short*)(ws + 540672 + 3 * 8388608 + 33554432);

    // zero h(0), c(0), flags each call
    hipMemsetAsync(ws, 0, 540672, stream);

    const int n4 = (4 * Hn * En) / 4;
    cvt_f32_bf16<<<n4 / 256, 256, 0, stream>>>(W_ih, Wih_b, n4);
    cvt_f32_bf16<<<n4 / 256, 256, 0, stream>>>(W_hh, Whh_b, n4);

    float* out_h = out + (size_t)Bn * Vn;
    float* out_c = out_h + Bn * Hn;

    // chunk 0: gather + standalone gemm
    gather_x<<<CHUNK * Bn, 256, 0, stream>>>(tokens, emb, Xb, 0);
    gemm_gin<<<32 * 32, 256, 0, stream>>>(Xb, Wih_b, Gb0);

    unsigned short* Gbuf[2] = {Gb0, Gb1};
    for (int c = 0; c < NCHUNK; ++c) {
        const int do_gemm = (c + 1 < NCHUNK) ? 1 : 0;
        if (do_gemm)
            gather_x<<<CHUNK * Bn, 256, 0, stream>>>(tokens, emb, Xb, (c + 1) * CHUNK);
        lstm_fused<<<256, 256, 0, stream>>>(Gbuf[c & 1], Gbuf[(c + 1) & 1], Xb,
                                            Wih_b, Whh_b, hbuf0, hbuf1,
                                            cst, flags, c * CHUNK, do_gemm,
                                            out_h, out_c);
    }

    classifier<<<(Vn + 63) / 64, 256, 0, stream>>>(hbuf0, W_cls, b_cls, out);
}